// Round 14
// baseline (346.916 us; speedup 1.0000x reference)
//
#include <hip/hip_runtime.h>
#include <stdint.h>

#define DEVI __device__ __forceinline__

typedef __attribute__((ext_vector_type(4))) float     f4v;
typedef __attribute__((ext_vector_type(8))) _Float16  h8;
typedef __attribute__((ext_vector_type(4))) _Float16  h4;
typedef unsigned int  u32;

static constexpr int   TQ = 1024, TKN = 512;
static constexpr float KEY_RATE = 1.385f;
static constexpr float QRY_RATE = 1.0f;
static constexpr float SCALE    = 0.04419417382415922f;   // sqrt(1/512)
static constexpr float INVC     = 0.05190512648261504f;   // log2(10000)/256

// ---------------- workspace layout (bytes) ----------------
static constexpr size_t OFF_MM   = 0;                                  // fp16 [512][512]  Mm = Wq Wk^T
static constexpr size_t OFF_NT   = OFF_MM  + (size_t)512*512*2;        // fp16 [512][512]  Nt = (Wv Wo)^T
static constexpr size_t OFF_WOT  = OFF_NT  + (size_t)512*512*2;        // f32  [512][512]  Wo^T
static constexpr size_t OFF_PEQ  = OFF_WOT + (size_t)512*512*4;        // f32  [1024][512]
static constexpr size_t OFF_W    = OFF_PEQ + (size_t)1024*512*4;       // f32  [512]
static constexpr size_t OFF_C    = OFF_W   + 2048;                     // f32  [512]
static constexpr size_t OFF_BQBK = OFF_C   + 2048;                     // f32  [1]
static constexpr size_t OFF_T    = OFF_BQBK + 256;                     // f32  [64][512] tvec_eff
static constexpr size_t OFF_KP   = OFF_T   + (size_t)64*512*4;         // fp16 [64][512][512] k' = keys+pe
static constexpr size_t OFF_MKT  = OFF_KP  + (size_t)64*512*512*2;     // fp16 [64][512][512] MKt[t][c]
static constexpr size_t OFF_PT   = OFF_MKT + (size_t)64*512*512*2;     // fp16 [64][512][512] Pt[e][t]
static constexpr size_t WS_NEED  = OFF_PT  + (size_t)64*512*512*2;     // ~105 MB
static constexpr size_t OFF_A16  = WS_NEED;                            // fp16 [64][1024][512] attn fp16
static constexpr size_t WS_BIG   = OFF_A16 + (size_t)64*1024*512*2;    // ~206 MB

#define WAITV(N) asm volatile("s_waitcnt vmcnt(" #N ")" ::: "memory")
#define WAITL()  asm volatile("s_waitcnt lgkmcnt(0)" ::: "memory")
#define SCHEDB() __builtin_amdgcn_sched_barrier(0)
#define BARRAW() __builtin_amdgcn_s_barrier()

// ---------------- core helpers ----------------
DEVI f4v mfma16(h8 a, h8 b, f4v c) {
  return __builtin_amdgcn_mfma_f32_16x16x32_f16(a, b, c, 0, 0, 0);
}

DEVI void gld16(void* lds, const void* g) {
  __builtin_amdgcn_global_load_lds(
      (const __attribute__((address_space(1))) unsigned int*)g,
      (__attribute__((address_space(3))) unsigned int*)lds, 16, 0, 0);
}

// B panel 512 rows x 32 cols fp16 (row stride 512): slot s holds chunk s^((r>>1)&3). 4 gld16/thread.
DEVI void stage_B512(char* Bbuf, const _Float16* B, int k0, int tid) {
#pragma unroll
  for (int it = 0; it < 4; ++it) {
    const int c = (it << 9) + tid;
    const int r = c >> 2, s = c & 3;
    const int sg = s ^ ((r >> 1) & 3);
    gld16(Bbuf + ((size_t)c << 4), B + (size_t)r * 512 + k0 + (sg << 3));
  }
}
// B panel 256 rows x 32 cols. 2 gld16/thread.
DEVI void stage_B256(char* Bbuf, const _Float16* B, int k0, int tid) {
#pragma unroll
  for (int it = 0; it < 2; ++it) {
    const int c = (it << 9) + tid;              // 0..1023
    const int r = c >> 2, s = c & 3;
    const int sg = s ^ ((r >> 1) & 3);
    gld16(Bbuf + ((size_t)c << 4), B + (size_t)r * 512 + k0 + (sg << 3));
  }
}
// A tile fp16 128 rows x 32 cols. 1 gld16/thread.
DEVI void stage_A16(char* Abuf, const _Float16* A, int k0, int tid) {
  const int r = tid >> 2, s = tid & 3;
  const int sg = s ^ ((r >> 1) & 3);
  gld16(Abuf + ((size_t)tid << 4), A + (size_t)r * 512 + k0 + (sg << 3));
}

// A fp32 128 rows: 2 f4v / thread
DEVI void loads_A32(f4v& x0, f4v& x1, const float* A, const float* add, int k0, int tid) {
  const int r = tid >> 2, c8 = (tid & 3) << 3;
  const float* p = A + (size_t)r * 512 + k0 + c8;
  x0 = *(const f4v*)p; x1 = *(const f4v*)(p + 4);
  if (add) {
    const float* q = add + (size_t)r * 512 + k0 + c8;
    x0 += *(const f4v*)q; x1 += *(const f4v*)(q + 4);
  }
}
DEVI void write_A32(char* Abuf, f4v x0, f4v x1, int tid) {
  const int r = tid >> 2;
  const int slot = (tid & 3) ^ ((r >> 1) & 3);
  h8 o;
#pragma unroll
  for (int i = 0; i < 4; ++i) { o[i] = (_Float16)x0[i]; o[4 + i] = (_Float16)x1[i]; }
  *(h8*)(Abuf + (r << 6) + (slot << 4)) = o;
}
// A fp32 64 rows: 1 f4v / thread
DEVI void loads_A64(f4v& x, const float* A, const float* add, int k0, int tid) {
  const int r = tid >> 3, c4 = tid & 7;
  x = *(const f4v*)(A + (size_t)r * 512 + k0 + (c4 << 2));
  if (add) x += *(const f4v*)(add + (size_t)r * 512 + k0 + (c4 << 2));
}
DEVI void write_A64(char* Abuf, f4v x, int tid) {
  const int r = tid >> 3, c4 = tid & 7;
  h4 o;
#pragma unroll
  for (int i = 0; i < 4; ++i) o[i] = (_Float16)x[i];
  const int slot = (c4 >> 1) ^ ((r >> 1) & 3);
  *(h4*)(Abuf + (r << 6) + (slot << 4) + ((c4 & 1) << 3)) = o;
}

DEVI void read_fragsA(const char* Ab, int wr, int lane, h8 (&a)[4]) {
  const int l15 = lane & 15, hi = lane >> 4;
#pragma unroll
  for (int mi = 0; mi < 4; ++mi) {
    const int r = wr * 64 + mi * 16 + l15;
    a[mi] = *(const h8*)(Ab + (r << 6) + ((hi ^ ((r >> 1) & 3)) << 4));
  }
}
// 4-frag B read at column base cb (elems)
DEVI void read_fragsB4(const char* Bb, int cb, int lane, h8 (&b)[4]) {
  const int l15 = lane & 15, hi = lane >> 4;
#pragma unroll
  for (int nj = 0; nj < 4; ++nj) {
    const int g = cb + nj * 16 + l15;
    b[nj] = *(const h8*)(Bb + (g << 6) + ((hi ^ ((g >> 1) & 3)) << 4));
  }
}
DEVI void read_fragsB8(const char* Bb, int wc, int lane, h8 (&b)[8]) {
  const int l15 = lane & 15, hi = lane >> 4;
#pragma unroll
  for (int nj = 0; nj < 8; ++nj) {
    const int g = wc * 128 + nj * 16 + l15;
    b[nj] = *(const h8*)(Bb + (g << 6) + ((hi ^ ((g >> 1) & 3)) << 4));
  }
}

#define MFMA_ALL4(a, bf, acc) do {                              \
  __builtin_amdgcn_s_setprio(1);                                \
  _Pragma("unroll") for (int mi = 0; mi < 4; ++mi)              \
  _Pragma("unroll") for (int nj = 0; nj < 4; ++nj)              \
      acc[mi][nj] = mfma16(a[mi], bf[nj], acc[mi][nj]);         \
  __builtin_amdgcn_s_setprio(0);                                \
} while (0)

#define MFMA_ALL8(a, bf, acc) do {                              \
  _Pragma("unroll") for (int mi = 0; mi < 4; ++mi)              \
  _Pragma("unroll") for (int nj = 0; nj < 8; ++nj)              \
      acc[mi][nj] = mfma16(a[mi], bf[nj], acc[mi][nj]);         \
} while (0)

// ---- REG256: A f32 128 rows reg-staged 2-deep, B256 gld 3-deep, counted vmcnt ----
// LDS: A0@0, A1@8K, B0@16K, B1@32K, B2@48K  (64KB)
#define REG256_PIPELINE(As, Ad, Bs, acc)                                           \
  {                                                                                \
    char* const Abf[2] = {lds, lds + 8192};                                        \
    char* const Bbf[3] = {lds + 16384, lds + 32768, lds + 49152};                  \
    f4v xa0, xa1, xb0, xb1;                                                        \
    loads_A32(xa0, xa1, As, Ad, 0, tid);                                           \
    loads_A32(xb0, xb1, As, Ad, 32, tid);                                          \
    SCHEDB();                                                                      \
    stage_B256(Bbf[0], Bs, 0, tid);                                                \
    stage_B256(Bbf[1], Bs, 32, tid);                                               \
    WAITV(6);                                                                      \
    write_A32(Abf[0], xa0, xa1, tid);                                              \
    WAITV(2); WAITL(); SCHEDB(); BARRAW(); SCHEDB();                               \
    _Pragma("unroll")                                                              \
    for (int k = 0; k < 16; ++k) {                                                 \
      if (k < 14) {                                                                \
        if ((k & 1) == 0) { loads_A32(xa0, xa1, As, Ad, (k + 2) * 32, tid); }      \
        else              { loads_A32(xb0, xb1, As, Ad, (k + 2) * 32, tid); }      \
        SCHEDB();                                                                  \
        stage_B256(Bbf[(k + 2) % 3], Bs, (k + 2) * 32, tid);                       \
      }                                                                            \
      h8 a[4], bf[4];                                                              \
      read_fragsA(Abf[k & 1], wr, lane, a);                                        \
      read_fragsB4(Bbf[k % 3], wc * 64, lane, bf);                                 \
      MFMA_ALL4(a, bf, acc);                                                       \
      if (k < 15) {                                                                \
        if (k < 14) { WAITV(4); } else { WAITV(2); }                               \
        if ((k & 1) == 0) write_A32(Abf[1], xb0, xb1, tid);                        \
        else              write_A32(Abf[0], xa0, xa1, tid);                        \
        if (k == 14) { WAITV(0); }                                                 \
        WAITL(); SCHEDB(); BARRAW(); SCHEDB();                                     \
      }                                                                            \
    }                                                                              \
  }

// ---- GLD256: A fp16 128 rows gld 3-deep, B256 gld 3-deep (sets of 3) ----
// LDS: A0@0, A1@8K, A2@16K, B0@24K, B1@40K, B2@56K  (72KB)
#define GLD256_PIPELINE(As, Bs, acc)                                               \
  {                                                                                \
    char* const Abf[3] = {lds, lds + 8192, lds + 16384};                           \
    char* const Bbf[3] = {lds + 24576, lds + 40960, lds + 57344};                  \
    stage_A16(Abf[0], As, 0, tid);  stage_B256(Bbf[0], Bs, 0, tid);                \
    stage_A16(Abf[1], As, 32, tid); stage_B256(Bbf[1], Bs, 32, tid);               \
    WAITV(3); SCHEDB(); BARRAW(); SCHEDB();                                        \
    _Pragma("unroll")                                                              \
    for (int k = 0; k < 16; ++k) {                                                 \
      if (k < 14) {                                                                \
        stage_A16(Abf[(k + 2) % 3], As, (k + 2) * 32, tid);                        \
        stage_B256(Bbf[(k + 2) % 3], Bs, (k + 2) * 32, tid);                       \
      }                                                                            \
      h8 a[4], bf[4];                                                              \
      read_fragsA(Abf[k % 3], wr, lane, a);                                        \
      read_fragsB4(Bbf[k % 3], wc * 64, lane, bf);                                 \
      MFMA_ALL4(a, bf, acc);                                                       \
      if (k < 14) { WAITV(3); } else if (k == 14) { WAITV(0); }                    \
      if (k < 15) { WAITL(); SCHEDB(); BARRAW(); SCHEDB(); }                       \
    }                                                                              \
  }

// reg-stage f32 tiles for the weight-product GEMM (512 threads, single-buffered)
DEVI void stage_f32_A(char* Abuf, const float* A, int k0, int tid) {
#pragma unroll
  for (int it = 0; it < 2; ++it) {
    const int idx = (it << 9) + tid;
    const int r = idx >> 3, c4 = idx & 7;
    f4v x = *(const f4v*)(A + (size_t)r * 512 + k0 + (c4 << 2));
    h4 o;
#pragma unroll
    for (int i = 0; i < 4; ++i) o[i] = (_Float16)x[i];
    const int slot = (c4 >> 1) ^ ((r >> 1) & 3);
    *(h4*)(Abuf + (r << 6) + (slot << 4) + ((c4 & 1) << 3)) = o;
  }
}
DEVI void stage_f32_B(char* Bbuf, const float* B, int k0, int tid) {
#pragma unroll
  for (int it = 0; it < 8; ++it) {
    const int idx = (it << 9) + tid;
    const int r = idx >> 3, c4 = idx & 7;
    f4v x = *(const f4v*)(B + (size_t)r * 512 + k0 + (c4 << 2));
    h4 o;
#pragma unroll
    for (int i = 0; i < 4; ++i) o[i] = (_Float16)x[i];
    const int slot = (c4 >> 1) ^ ((r >> 1) & 3);
    *(h4*)(Bbuf + (r << 6) + (slot << 4) + ((c4 & 1) << 3)) = o;
  }
}

// ---------------- prepA: wvec/bqbk + PEQ + Wo^T  (256 threads) ----------------
__global__ __launch_bounds__(256) void k_prepA(
    const float* __restrict__ Wk, const float* __restrict__ bq,
    const float* __restrict__ bk,
    const float* __restrict__ Wo,
    const void* __restrict__ fpos_raw,
    float* __restrict__ wvec, float* __restrict__ bqbk,
    float* __restrict__ PEQ, float* __restrict__ WoT) {
  const int bid = blockIdx.x, tid = threadIdx.x;
  if (bid < 128) {
    const int wid = tid >> 6, lane = tid & 63;
    const int row = bid * 4 + wid;
    const float* p = Wk + (size_t)row * 512 + lane * 8;
    const f4v a = *(const f4v*)p, c = *(const f4v*)(p + 4);
    const f4v b0 = *(const f4v*)(bq + lane * 8), b1 = *(const f4v*)(bq + lane * 8 + 4);
    float d = a[0]*b0[0]+a[1]*b0[1]+a[2]*b0[2]+a[3]*b0[3]
            + c[0]*b1[0]+c[1]*b1[1]+c[2]*b1[2]+c[3]*b1[3];
#pragma unroll
    for (int off = 32; off; off >>= 1) d += __shfl_xor(d, off);
    if (lane == 0) wvec[row] = d;
  } else if (bid == 128) {
    __shared__ float red[256];
    red[tid] = bq[tid] * bk[tid] + bq[tid + 256] * bk[tid + 256];
    __syncthreads();
    if (tid == 0) { float s = 0.f; for (int h = 0; h < 256; ++h) s += red[h]; bqbk[0] = s; }
  } else if (bid < 129 + 2048) {
    const u32* fp = (const u32*)fpos_raw;
    const bool is64 = (fp[1] == 0);
    const int t = (bid - 129) * 256 + tid;
    const int tq = t >> 9, d = t & 511;
    const int pos = (int)(is64 ? fp[2 * tq] : fp[tq]);
    float pe = 0.f;
    if (pos != 0) {
      const float invf = exp2f(-(float)(d >> 1) * INVC);
      const float ang  = ((float)pos * QRY_RATE) * invf;
      pe = (d & 1) ? cosf(ang) : sinf(ang);
    }
    PEQ[t] = pe;
  } else {
    __shared__ float t[32][33];
    const int local = bid - 2177;
    const int bx = local & 15, by = local >> 4;
    const int tx = tid & 31, ty = tid >> 5;
    const int x = bx * 32 + tx;
#pragma unroll
    for (int j = 0; j < 4; ++j)
      t[ty + 8 * j][tx] = Wo[(size_t)(by * 32 + ty + 8 * j) * 512 + x];
    __syncthreads();
    const int x2 = by * 32 + tx;
#pragma unroll
    for (int j = 0; j < 4; ++j)
      WoT[(size_t)(bx * 32 + ty + 8 * j) * 512 + x2] = t[tx][ty + 8 * j];
  }
}

// ---------------- prepB: weight-product GEMMs + key prep + cvec  (512 threads) ----------------
__global__ __launch_bounds__(512) void k_prepB(
    const float* __restrict__ Wq, const float* __restrict__ Wk,
    const float* __restrict__ WoT, const float* __restrict__ Wv,
    const float* __restrict__ keys, const void* __restrict__ tpos_raw,
    const void* __restrict__ mask_raw,
    const float* __restrict__ wvec, const float* __restrict__ bqbk,
    const float* __restrict__ bv, const float* __restrict__ bo,
    _Float16* __restrict__ Mm, _Float16* __restrict__ Nt,
    _Float16* __restrict__ kp, float* __restrict__ tvec,
    float* __restrict__ cvec) {
  __shared__ char lds[40960];
  const int bid = blockIdx.x, tid = threadIdx.x;
  const int lane = tid & 63, wid = tid >> 6;
  if (bid < 8) {
    char *Ab = lds, *Bb = lds + 8192;
    const int wr = wid >> 2, wc = wid & 3;
    const int x = bid & 3, y = bid >> 2;
    const float* A = (y == 0 ? Wq : WoT) + (size_t)x * 128 * 512;
    const float* B = (y == 0 ? Wk : Wv);
    _Float16* out = (y == 0 ? Mm : Nt) + (size_t)x * 128 * 512;
    f4v acc[4][8] = {};
    for (int ks = 0; ks < 16; ++ks) {
      stage_f32_A(Ab, A, ks * 32, tid);
      stage_f32_B(Bb, B, ks * 32, tid);
      __syncthreads();
      h8 a[4], bf[8];
      read_fragsA(Ab, wr, lane, a);
      read_fragsB8(Bb, wc, lane, bf);
      MFMA_ALL8(a, bf, acc);
      __syncthreads();
    }
    const int l15 = lane & 15, hi = lane >> 4;
#pragma unroll
    for (int mi = 0; mi < 4; ++mi)
#pragma unroll
      for (int nj = 0; nj < 8; ++nj) {
        const int col = wc * 128 + nj * 16 + l15;
#pragma unroll
        for (int j = 0; j < 4; ++j) {
          const int row = wr * 64 + mi * 16 + hi * 4 + j;
          out[(size_t)row * 512 + col] = (_Float16)acc[mi][nj][j];
        }
      }
  } else if (bid < 4104) {
    const u32* tp = (const u32*)tpos_raw;
    const bool is64 = (tp[1] == 0);
    const int row = (bid - 8) * 8 + wid;
    const int pos = (int)(is64 ? tp[2 * row] : tp[row]);
    const int d0  = lane * 8;
    const float* src = keys + (size_t)row * 512 + d0;
    const f4v a = *(const f4v*)src, b = *(const f4v*)(src + 4);
    float x[8] = {a[0], a[1], a[2], a[3], b[0], b[1], b[2], b[3]};
    if (pos != 0) {
      const float pw = (float)pos * KEY_RATE;
#pragma unroll
      for (int u = 0; u < 4; ++u) {
        const float invf = exp2f(-(float)(lane * 4 + u) * INVC);
        const float ang  = pw * invf;
        x[2*u]   += sinf(ang);
        x[2*u+1] += cosf(ang);
      }
    }
    const f4v w0 = *(const f4v*)(wvec + d0), w1 = *(const f4v*)(wvec + d0 + 4);
    float dot = 0.f;
#pragma unroll
    for (int i = 0; i < 4; ++i) dot += x[i] * w0[i] + x[4+i] * w1[i];
#pragma unroll
    for (int off = 32; off; off >>= 1) dot += __shfl_xor(dot, off);
    if (lane == 0) {
      const u32* m32 = (const u32*)mask_raw;
      const bool is32 = (m32[448] != 0);
      const bool mk = is32 ? (m32[row] != 0)
                           : (((const unsigned char*)mask_raw)[row] != 0);
      tvec[row] = mk ? -1e30f : (dot + bqbk[0]);
    }
    h8 o;
#pragma unroll
    for (int i = 0; i < 8; ++i) o[i] = (_Float16)x[i];
    *(h8*)(kp + (size_t)row * 512 + d0) = o;
  } else {
    const int row = (bid - 4104) * 8 + wid;
    const float* p = WoT + (size_t)row * 512 + lane * 8;
    const f4v a = *(const f4v*)p, c = *(const f4v*)(p + 4);
    const f4v b0 = *(const f4v*)(bv + lane * 8), b1 = *(const f4v*)(bv + lane * 8 + 4);
    float d = a[0]*b0[0]+a[1]*b0[1]+a[2]*b0[2]+a[3]*b0[3]
            + c[0]*b1[0]+c[1]*b1[1]+c[2]*b1[2]+c[3]*b1[3];
#pragma unroll
    for (int off = 32; off; off >>= 1) d += __shfl_xor(d, off);
    if (lane == 0) cvec[row] = SCALE * d + bo[row];
  }
}

// ---------------- mk + pv merged: BN=256, acc[4][4], 2 blocks/CU ----------------
__global__ __launch_bounds__(512, 4) void k_mkpv(
    const _Float16* __restrict__ kp, const _Float16* __restrict__ Mm,
    const float* __restrict__ values, const _Float16* __restrict__ Nt,
    _Float16* __restrict__ MKt, _Float16* __restrict__ Pt) {
  __shared__ char lds[73728];
  const int bid = blockIdx.x, tid = threadIdx.x;
  const int lane = tid & 63, wid = tid >> 6;
  const int wr = wid >> 2, wc = wid & 3;
  const int l15 = lane & 15, hi = lane >> 4;
  f4v acc[4][4] = {};
  if (bid < 512) {                       // MKt[t][c] = kp @ Mm^T   (nt half)
    const int nt = bid & 1, tt = (bid >> 1) & 3, b = bid >> 3;
    const _Float16* As = kp + ((size_t)b * TKN + tt * 128) * 512;
    const _Float16* Bs = Mm + (size_t)nt * 256 * 512;
    GLD256_PIPELINE(As, Bs, acc);
    _Float16* Ob = MKt + (size_t)b * TKN * 512 + (size_t)tt * 128 * 512;
#pragma unroll
    for (int mi = 0; mi < 4; ++mi)
#pragma unroll
      for (int nj = 0; nj < 4; ++nj) {
        const int col = nt * 256 + wc * 64 + nj * 16 + l15;
#pragma unroll
        for (int j = 0; j < 4; ++j) {
          const int row = wr * 64 + mi * 16 + hi * 4 + j;
          Ob[(size_t)row * 512 + col] = (_Float16)acc[mi][nj][j];
        }
      }
  } else {                               // Pt[e][t] = (values @ N)^T  (nt half)
    const int idx = bid - 512;
    const int nt = idx & 1, rt = (idx >> 1) & 3, b = idx >> 3;
    const float* As = values + ((size_t)b * TKN + rt * 128) * 512;
    const float* Ad = nullptr;
    const _Float16* Bs = Nt + (size_t)nt * 256 * 512;
    REG256_PIPELINE(As, Ad, Bs, acc);
    _Float16* Pb = Pt + (size_t)b * 512 * 512;
#pragma unroll
    for (int mi = 0; mi < 4; ++mi)
#pragma unroll
      for (int nj = 0; nj < 4; ++nj) {
        const int col = nt * 256 + wc * 64 + nj * 16 + l15;
        const int t0  = rt * 128 + wr * 64 + mi * 16 + hi * 4;
        h4 o;
#pragma unroll
        for (int j = 0; j < 4; ++j) o[j] = (_Float16)acc[mi][nj][j];
        *(h4*)(Pb + (size_t)col * 512 + t0) = o;
      }
  }
}

// ---------------- scores + fused softmax: BM=64, 8 column-waves, acc[4][4] ----------------
__global__ __launch_bounds__(512, 4) void k_scores(
    const float* __restrict__ query, const float* __restrict__ PEQ,
    const _Float16* __restrict__ MKt, const float* __restrict__ tve,
    float* __restrict__ attn, _Float16* __restrict__ a16) {
  __shared__ char lds[73728];
  const int tid = threadIdx.x, lane = tid & 63, wc = tid >> 6;  // wc 0..7
  const int bid = blockIdx.x;
  const int xcd = bid & 7, i = bid >> 3;
  const int qt = i & 15, b = xcd * 8 + (i >> 4);
  const float* As = query + ((size_t)b * TQ + qt * 64) * 512;
  const float* Ad = PEQ + (size_t)(qt * 64) * 512;
  const _Float16* Bs = MKt + (size_t)b * TKN * 512;
  const int l15 = lane & 15, hi = lane >> 4;
  float tv[4];
#pragma unroll
  for (int nj = 0; nj < 4; ++nj) tv[nj] = tve[b * TKN + wc * 64 + nj * 16 + l15];

  // ---- phase 1: A 2-deep reg-staged (64-row), B512 2-deep gld, counted vmcnt ----
  f4v acc[4][4] = {};
  {
    char* const Abf[2] = {lds, lds + 4096};
    char* const Bbf[2] = {lds + 8192, lds + 40960};
    f4v xa, xb;
    loads_A64(xa, As, Ad, 0, tid);
    SCHEDB();
    stage_B512(Bbf[0], Bs, 0, tid);
    loads_A64(xb, As, Ad, 32, tid);
    WAITV(5);                                   // xa landed (B0 4 + xb 1 outstanding)
    write_A64(Abf[0], xa, tid);
    WAITV(1);                                   // B0 landed (keep xb)
    WAITL(); SCHEDB(); BARRAW(); SCHEDB();
#pragma unroll
    for (int k = 0; k < 16; ++k) {
      if (k < 15) stage_B512(Bbf[(k + 1) & 1], Bs, (k + 1) * 32, tid);
      if (k < 14) {
        if ((k & 1) == 0) { loads_A64(xa, As, Ad, (k + 2) * 32, tid); }
        else              { loads_A64(xb, As, Ad, (k + 2) * 32, tid); }
      }
      h8 a[4], bf[4];
      read_fragsA(Abf[k & 1], 0, lane, a);
      read_fragsB4(Bbf[k & 1], wc * 64, lane, bf);
      MFMA_ALL4(a, bf, acc);
      if (k < 15) {
        if (k < 14) { WAITV(5); } else { WAITV(4); }   // x_{k+1} landed
        if ((k & 1) == 0) write_A64(Abf[1], xb, tid);
        else              write_A64(Abf[0], xa, tid);
        if (k < 14) { WAITV(1); } else { WAITV(0); }   // B(k+1) landed
        WAITL(); SCHEDB(); BARRAW(); SCHEDB();
      }
    }
  }

  // ---- fused softmax over 512-wide rows, 8-wave reduce ----
  float* red  = (float*)lds;            // [64][8]  (A0 region, last read k=14)
  float* red2 = (float*)(lds + 2048);
#pragma unroll
  for (int mi = 0; mi < 4; ++mi)
#pragma unroll
    for (int nj = 0; nj < 4; ++nj) {
      const float t = tv[nj];
#pragma unroll
      for (int j = 0; j < 4; ++j) acc[mi][nj][j] += t;
    }
  float mrow[4][4];
#pragma unroll
  for (int mi = 0; mi < 4; ++mi)
#pragma unroll
    for (int j = 0; j < 4; ++j) {
      float m = acc[mi][0][j];
#pragma unroll
      for (int nj = 1; nj < 4; ++nj) m = fmaxf(m, acc[mi][nj][j]);
      m = fmaxf(m, __shfl_xor(m, 1)); m = fmaxf(m, __shfl_xor(m, 2));
      m = fmaxf(m, __shfl_xor(m, 4)); m = fmaxf(m, __shfl_xor(m, 8));
      mrow[mi][j] = m;
    }
  if (l15 == 0) {
#pragma unroll
    for (int mi = 0; mi < 4; ++mi)
#pragma unroll
      for (int j = 0; j < 4; ++j)
        red[(mi * 16 + hi * 4 + j) * 8 + wc] = mrow[mi][j];
  }
  __syncthreads();
#pragma unroll
  for (int mi = 0; mi < 4; ++mi)
#pragma unroll
    for (int j = 0; j < 4; ++j) {
      const int row = mi * 16 + hi * 4 + j;
      const f4v r0 = *(const f4v*)(red + row * 8);
      const f4v r1 = *(const f4v*)(red + row * 8 + 4);
      mrow[mi][j] = fmaxf(fmaxf(fmaxf(r0[0], r0[1]), fmaxf(r0[2], r0[3])),
                          fmaxf(fmaxf(r1[0], r1[1]), fmaxf(r1[2], r1[3])));
    }
  float srow[4][4];
#pragma unroll
  for (int mi = 0; mi < 4; ++mi)
#pragma unroll
    for (int j = 0; j < 4; ++j) {
      float s = 0.f;
      const float m = mrow[mi][j];
#pragma unroll
      for (int nj = 0; nj < 4; ++nj) {
        const float e = expf(acc[mi][nj][j] - m);
        acc[mi][nj][j] = e; s += e;
      }
      s += __shfl_xor(s, 1); s += __shfl_xor(s, 2);
      s += __shfl_xor(s, 4); s += __shfl_xor(s, 8);
      srow[mi][j] = s;
    }
  if (l15 == 0) {
#pragma unroll
    for (int mi = 0; mi < 4; ++mi)
#pragma unroll
      for (int j = 0; j < 4; ++j)
        red2[(mi * 16 + hi * 4 + j) * 8 + wc] = srow[mi][j];
  }
  __syncthreads();
  float* Ao = attn + ((size_t)b * TQ + qt * 64) * 512;
  _Float16* Ah = a16 ? a16 + ((size_t)b * TQ + qt * 64) * 512 : nullptr;
#pragma unroll
  for (int mi = 0; mi < 4; ++mi)
#pragma unroll
    for (int j = 0; j < 4; ++j) {
      const int row = mi * 16 + hi * 4 + j;
      const f4v s0 = *(const f4v*)(red2 + row * 8);
      const f4v s1 = *(const f4v*)(red2 + row * 8 + 4);
      const float rinv = 1.f / (s0[0] + s0[1] + s0[2] + s0[3] +
                                s1[0] + s1[1] + s1[2] + s1[3]);
#pragma unroll
      for (int nj = 0; nj < 4; ++nj) {
        const float v = acc[mi][nj][j] * rinv;
        const int col = wc * 64 + nj * 16 + l15;
        Ao[(size_t)row * 512 + col] = v;
        if (Ah) Ah[(size_t)row * 512 + col] = (_Float16)v;
      }
    }
}

// ---------------- out = SCALE * attn @ Pt^T + cvec: BN=256, acc[4][4] ----------------
template <int A16P>
__global__ __launch_bounds__(512, 4) void k_final(
    const float* __restrict__ attn, const _Float16* __restrict__ attn16,
    const _Float16* __restrict__ Pt, const float* __restrict__ cvec,
    float* __restrict__ outp) {
  __shared__ char lds[73728];
  const int tid = threadIdx.x, lane = tid & 63, wid = tid >> 6;
  const int wr = wid >> 2, wc = wid & 3;
  const int bid = blockIdx.x;
  const int xcd = bid & 7, i = bid >> 3;
  const int qt = i & 7, nt = (i >> 3) & 1, b = xcd * 8 + (i >> 4);
  const _Float16* Bs = Pt + (size_t)b * 512 * 512 + (size_t)nt * 256 * 512;
  const int l15 = lane & 15, hi = lane >> 4;
  f4v acc[4][4] = {};
  if (A16P) {
    const _Float16* As = attn16 + ((size_t)b * TQ + qt * 128) * 512;
    GLD256_PIPELINE(As, Bs, acc);
  } else {
    const float* As = attn + ((size_t)b * TQ + qt * 128) * 512;
    const float* Ad = nullptr;
    REG256_PIPELINE(As, Ad, Bs, acc);
  }
  float cv[4];
#pragma unroll
  for (int nj = 0; nj < 4; ++nj) cv[nj] = cvec[nt * 256 + wc * 64 + nj * 16 + l15];
  float* Ob = outp + ((size_t)b * TQ + qt * 128) * 512;
#pragma unroll
  for (int mi = 0; mi < 4; ++mi)
#pragma unroll
    for (int nj = 0; nj < 4; ++nj) {
      const int col = nt * 256 + wc * 64 + nj * 16 + l15;
#pragma unroll
      for (int j = 0; j < 4; ++j) {
        const int row = wr * 64 + mi * 16 + hi * 4 + j;
        Ob[(size_t)row * 512 + col] = SCALE * acc[mi][nj][j] + cv[nj];
      }
    }
}

// ---------------- launcher ----------------
extern "C" void kernel_launch(void* const* d_in, const int* in_sizes, int n_in,
                              void* d_out, int out_size, void* d_ws, size_t ws_size,
                              hipStream_t stream) {
  (void)in_sizes; (void)n_in; (void)out_size;
  if (ws_size < WS_NEED) return;
  const bool big = (ws_size >= WS_BIG);

  const float* query  = (const float*)d_in[0];
  const float* keys   = (const float*)d_in[1];
  const float* values = (const float*)d_in[2];
  const void*  tpos   = d_in[3];
  const void*  fpos   = d_in[4];
  const void*  mask   = d_in[5];
  const float* Wq = (const float*)d_in[6];
  const float* bq = (const float*)d_in[7];
  const float* Wk = (const float*)d_in[8];
  const float* bk = (const float*)d_in[9];
  const float* Wv = (const float*)d_in[10];
  const float* bv = (const float*)d_in[11];
  const float* Wo = (const float*)d_in[12];
  const float* bo = (const float*)d_in[13];

  char* ws = (char*)d_ws;
  _Float16* Mm   = (_Float16*)(ws + OFF_MM);
  _Float16* Nt   = (_Float16*)(ws + OFF_NT);
  float*    WoT  = (float*)   (ws + OFF_WOT);
  float*    PEQ  = (float*)   (ws + OFF_PEQ);
  float*    wvec = (float*)   (ws + OFF_W);
  float*    cvec = (float*)   (ws + OFF_C);
  float*    bqbk = (float*)   (ws + OFF_BQBK);
  float*    tvec = (float*)   (ws + OFF_T);
  _Float16* kp   = (_Float16*)(ws + OFF_KP);
  _Float16* MKt  = (_Float16*)(ws + OFF_MKT);
  _Float16* Pt   = (_Float16*)(ws + OFF_PT);
  _Float16* a16  = big ? (_Float16*)(ws + OFF_A16) : nullptr;

  float* outp = (float*)d_out;
  float* attn = outp + (size_t)64 * TQ * 512;   // output 1 region

  k_prepA<<<2433, 256, 0, stream>>>(Wk, bq, bk, Wo, fpos, wvec, bqbk, PEQ, WoT);
  k_prepB<<<4168, 512, 0, stream>>>(Wq, Wk, WoT, Wv, keys, tpos, mask,
                                    wvec, bqbk, bv, bo, Mm, Nt, kp, tvec, cvec);
  k_mkpv <<<1024, 512, 0, stream>>>(kp, Mm, values, Nt, MKt, Pt);
  k_scores<<<1024, 512, 0, stream>>>(query, PEQ, MKt, tvec, attn, a16);
  if (big) k_final<1><<<1024, 512, 0, stream>>>(attn, a16, Pt, cvec, outp);
  else     k_final<0><<<1024, 512, 0, stream>>>(attn, a16, Pt, cvec, outp);
}

// Round 15
// 316.080 us; speedup vs baseline: 1.0976x; 1.0976x over previous
//
#include <hip/hip_runtime.h>
#include <stdint.h>

#define DEVI __device__ __forceinline__

typedef __attribute__((ext_vector_type(4))) float     f4v;
typedef __attribute__((ext_vector_type(8))) _Float16  h8;
typedef __attribute__((ext_vector_type(4))) _Float16  h4;
typedef unsigned int  u32;

static constexpr int   TQ = 1024, TKN = 512;
static constexpr float KEY_RATE = 1.385f;
static constexpr float QRY_RATE = 1.0f;
static constexpr float SCALE    = 0.04419417382415922f;   // sqrt(1/512)
static constexpr float INVC     = 0.05190512648261504f;   // log2(10000)/256

// ---------------- workspace layout (bytes) ----------------
static constexpr size_t OFF_MM   = 0;                                  // fp16 [512][512]  Mm = Wq Wk^T
static constexpr size_t OFF_NT   = OFF_MM  + (size_t)512*512*2;        // fp16 [512][512]  Nt = (Wv Wo)^T
static constexpr size_t OFF_WOT  = OFF_NT  + (size_t)512*512*2;        // f32  [512][512]  Wo^T
static constexpr size_t OFF_PEQ  = OFF_WOT + (size_t)512*512*4;        // f32  [1024][512]
static constexpr size_t OFF_W    = OFF_PEQ + (size_t)1024*512*4;       // f32  [512]
static constexpr size_t OFF_C    = OFF_W   + 2048;                     // f32  [512]
static constexpr size_t OFF_BQBK = OFF_C   + 2048;                     // f32  [1]
static constexpr size_t OFF_T    = OFF_BQBK + 256;                     // f32  [64][512] tvec_eff
static constexpr size_t OFF_KP   = OFF_T   + (size_t)64*512*4;         // fp16 [64][512][512] k' = keys+pe
static constexpr size_t OFF_MKT  = OFF_KP  + (size_t)64*512*512*2;     // fp16 [64][512][512] MKt[t][c]
static constexpr size_t OFF_PT   = OFF_MKT + (size_t)64*512*512*2;     // fp16 [64][512][512] Pt[e][t]
static constexpr size_t WS_NEED  = OFF_PT  + (size_t)64*512*512*2;     // ~105 MB
static constexpr size_t OFF_A16  = WS_NEED;                            // fp16 [64][1024][512] attn fp16
static constexpr size_t WS_BIG   = OFF_A16 + (size_t)64*1024*512*2;    // ~206 MB

#define WAITV(N) asm volatile("s_waitcnt vmcnt(" #N ")" ::: "memory")
#define WAITL()  asm volatile("s_waitcnt lgkmcnt(0)" ::: "memory")
#define SCHEDB() __builtin_amdgcn_sched_barrier(0)
#define BARRAW() __builtin_amdgcn_s_barrier()

// ---------------- core helpers (BM=128, BN=512, BK=32 sub-tiles) ----------------
DEVI f4v mfma16(h8 a, h8 b, f4v c) {
  return __builtin_amdgcn_mfma_f32_16x16x32_f16(a, b, c, 0, 0, 0);
}

DEVI void gld16(void* lds, const void* g) {
  __builtin_amdgcn_global_load_lds(
      (const __attribute__((address_space(1))) unsigned int*)g,
      (__attribute__((address_space(3))) unsigned int*)lds, 16, 0, 0);
}

// B panel: 512 rows x 32 cols fp16 (row stride 512): slot s holds chunk s^((r>>1)&3). 4 gld16/thread.
DEVI void stage_B(char* Bbuf, const _Float16* B, int k0, int tid) {
#pragma unroll
  for (int it = 0; it < 4; ++it) {
    const int c = (it << 9) + tid;              // 0..2047 16B chunks
    const int r = c >> 2, s = c & 3;
    const int sg = s ^ ((r >> 1) & 3);
    gld16(Bbuf + ((size_t)c << 4), B + (size_t)r * 512 + k0 + (sg << 3));
  }
}

// A tile fp16: 128 rows x 32 cols (row stride 512). 1 gld16/thread.
DEVI void stage_A16(char* Abuf, const _Float16* A, int k0, int tid) {
  const int r = tid >> 2, s = tid & 3;
  const int sg = s ^ ((r >> 1) & 3);
  gld16(Abuf + ((size_t)tid << 4), A + (size_t)r * 512 + k0 + (sg << 3));
}

// A tile fp32 source: issue loads (early) ...
DEVI void loads_A32(f4v& x0, f4v& x1, const float* A, const float* add, int k0, int tid) {
  const int r = tid >> 2, c8 = (tid & 3) << 3;
  const float* p = A + (size_t)r * 512 + k0 + c8;
  x0 = *(const f4v*)p; x1 = *(const f4v*)(p + 4);
  if (add) {
    const float* q = add + (size_t)r * 512 + k0 + c8;
    x0 += *(const f4v*)q; x1 += *(const f4v*)(q + 4);
  }
}
// ... convert+write (late)
DEVI void write_A32(char* Abuf, f4v x0, f4v x1, int tid) {
  const int r = tid >> 2;
  const int slot = (tid & 3) ^ ((r >> 1) & 3);
  h8 o;
#pragma unroll
  for (int i = 0; i < 4; ++i) { o[i] = (_Float16)x0[i]; o[4 + i] = (_Float16)x1[i]; }
  *(h8*)(Abuf + (r << 6) + (slot << 4)) = o;
}

DEVI void read_fragsA(const char* Ab, int wr, int lane, h8 (&a)[4]) {
  const int l15 = lane & 15, hi = lane >> 4;
#pragma unroll
  for (int mi = 0; mi < 4; ++mi) {
    const int r = wr * 64 + mi * 16 + l15;
    a[mi] = *(const h8*)(Ab + (r << 6) + ((hi ^ ((r >> 1) & 3)) << 4));
  }
}
DEVI void read_fragsB(const char* Bb, int wc, int lane, h8 (&b)[8]) {
  const int l15 = lane & 15, hi = lane >> 4;
#pragma unroll
  for (int nj = 0; nj < 8; ++nj) {
    const int g = wc * 128 + nj * 16 + l15;
    b[nj] = *(const h8*)(Bb + (g << 6) + ((hi ^ ((g >> 1) & 3)) << 4));
  }
}

// T5: setprio around the MFMA cluster
#define MFMA_ALL(a, bf, acc) do {                               \
  __builtin_amdgcn_s_setprio(1);                                \
  _Pragma("unroll") for (int mi = 0; mi < 4; ++mi)              \
  _Pragma("unroll") for (int nj = 0; nj < 8; ++nj)              \
      acc[mi][nj] = mfma16(a[mi], bf[nj], acc[mi][nj]);         \
  __builtin_amdgcn_s_setprio(0);                                \
} while (0)

// ---- REG-A paired pipeline: 8 periods, 2 BK=32 sub-tiles per barrier ----
// LDS: A 4x8KB @0..32K, B 4x32KB @32K..160K  (160KB exact)
#define REG_PIPELINE(As, Ad, Bs, acc)                                              \
  {                                                                                \
    char* const Abf[4] = {lds, lds + 8192, lds + 16384, lds + 24576};              \
    char* const Bbf[4] = {lds + 32768, lds + 65536, lds + 98304, lds + 131072};    \
    f4v xa0, xa1, xb0, xb1;                                                        \
    stage_B(Bbf[0], Bs, 0, tid);                                                   \
    stage_B(Bbf[1], Bs, 32, tid);                                                  \
    loads_A32(xa0, xa1, As, Ad, 0, tid);                                           \
    loads_A32(xb0, xb1, As, Ad, 32, tid);                                          \
    SCHEDB();                                                                      \
    WAITV(0);                                                                      \
    write_A32(Abf[0], xa0, xa1, tid);                                              \
    write_A32(Abf[1], xb0, xb1, tid);                                              \
    WAITL(); SCHEDB(); BARRAW(); SCHEDB();                                         \
    _Pragma("unroll")                                                              \
    for (int p = 0; p < 8; ++p) {                                                  \
      const int s0 = 2 * p, s1 = 2 * p + 1;                                        \
      if (p < 7) {                                                                 \
        stage_B(Bbf[(s0 + 2) & 3], Bs, (s0 + 2) * 32, tid);                        \
        stage_B(Bbf[(s1 + 2) & 3], Bs, (s1 + 2) * 32, tid);                        \
        loads_A32(xa0, xa1, As, Ad, (s0 + 2) * 32, tid);                           \
        loads_A32(xb0, xb1, As, Ad, (s1 + 2) * 32, tid);                           \
        SCHEDB();                                                                  \
      }                                                                            \
      h8 a[4], bf[8];                                                              \
      read_fragsA(Abf[s0 & 3], wr, lane, a);                                       \
      read_fragsB(Bbf[s0 & 3], wc, lane, bf);                                      \
      MFMA_ALL(a, bf, acc);                                                        \
      read_fragsA(Abf[s1 & 3], wr, lane, a);                                       \
      read_fragsB(Bbf[s1 & 3], wc, lane, bf);                                      \
      MFMA_ALL(a, bf, acc);                                                        \
      if (p < 7) {                                                                 \
        WAITV(0);                                                                  \
        write_A32(Abf[(s0 + 2) & 3], xa0, xa1, tid);                               \
        write_A32(Abf[(s1 + 2) & 3], xb0, xb1, tid);                               \
        WAITL(); SCHEDB(); BARRAW(); SCHEDB();                                     \
      }                                                                            \
    }                                                                              \
  }

// ---- GLD-A paired pipeline: A fp16 gld16, same 8-period structure ----
#define GLD_PIPELINE(As, Bs, acc)                                                  \
  {                                                                                \
    char* const Abf[4] = {lds, lds + 8192, lds + 16384, lds + 24576};              \
    char* const Bbf[4] = {lds + 32768, lds + 65536, lds + 98304, lds + 131072};    \
    stage_A16(Abf[0], As, 0, tid);  stage_B(Bbf[0], Bs, 0, tid);                   \
    stage_A16(Abf[1], As, 32, tid); stage_B(Bbf[1], Bs, 32, tid);                  \
    WAITV(0); SCHEDB(); BARRAW(); SCHEDB();                                        \
    _Pragma("unroll")                                                              \
    for (int p = 0; p < 8; ++p) {                                                  \
      const int s0 = 2 * p, s1 = 2 * p + 1;                                        \
      if (p < 7) {                                                                 \
        stage_A16(Abf[(s0 + 2) & 3], As, (s0 + 2) * 32, tid);                      \
        stage_B(Bbf[(s0 + 2) & 3], Bs, (s0 + 2) * 32, tid);                        \
        stage_A16(Abf[(s1 + 2) & 3], As, (s1 + 2) * 32, tid);                      \
        stage_B(Bbf[(s1 + 2) & 3], Bs, (s1 + 2) * 32, tid);                        \
      }                                                                            \
      h8 a[4], bf[8];                                                              \
      read_fragsA(Abf[s0 & 3], wr, lane, a);                                       \
      read_fragsB(Bbf[s0 & 3], wc, lane, bf);                                      \
      MFMA_ALL(a, bf, acc);                                                        \
      read_fragsA(Abf[s1 & 3], wr, lane, a);                                       \
      read_fragsB(Bbf[s1 & 3], wc, lane, bf);                                      \
      MFMA_ALL(a, bf, acc);                                                        \
      if (p < 7) { WAITV(0); WAITL(); SCHEDB(); BARRAW(); SCHEDB(); }              \
    }                                                                              \
  }

// reg-stage f32 tiles for the tiny weight-product GEMM (single-buffered)
DEVI void stage_f32_A(char* Abuf, const float* A, int k0, int tid) {
#pragma unroll
  for (int it = 0; it < 2; ++it) {
    const int idx = (it << 9) + tid;
    const int r = idx >> 3, c4 = idx & 7;
    f4v x = *(const f4v*)(A + (size_t)r * 512 + k0 + (c4 << 2));
    h4 o;
#pragma unroll
    for (int i = 0; i < 4; ++i) o[i] = (_Float16)x[i];
    const int slot = (c4 >> 1) ^ ((r >> 1) & 3);
    *(h4*)(Abuf + (r << 6) + (slot << 4) + ((c4 & 1) << 3)) = o;
  }
}
DEVI void stage_f32_B(char* Bbuf, const float* B, int k0, int tid) {
#pragma unroll
  for (int it = 0; it < 8; ++it) {
    const int idx = (it << 9) + tid;
    const int r = idx >> 3, c4 = idx & 7;
    f4v x = *(const f4v*)(B + (size_t)r * 512 + k0 + (c4 << 2));
    h4 o;
#pragma unroll
    for (int i = 0; i < 4; ++i) o[i] = (_Float16)x[i];
    const int slot = (c4 >> 1) ^ ((r >> 1) & 3);
    *(h4*)(Bbuf + (r << 6) + (slot << 4) + ((c4 & 1) << 3)) = o;
  }
}

// ---------------- prepA: wvec/bqbk + PEQ + Wo^T  (256 threads) ----------------
__global__ __launch_bounds__(256) void k_prepA(
    const float* __restrict__ Wk, const float* __restrict__ bq,
    const float* __restrict__ bk,
    const float* __restrict__ Wo,
    const void* __restrict__ fpos_raw,
    float* __restrict__ wvec, float* __restrict__ bqbk,
    float* __restrict__ PEQ, float* __restrict__ WoT) {
  const int bid = blockIdx.x, tid = threadIdx.x;
  if (bid < 128) {                       // wvec: 4 rows/block, 1 per wave
    const int wid = tid >> 6, lane = tid & 63;
    const int row = bid * 4 + wid;
    const float* p = Wk + (size_t)row * 512 + lane * 8;
    const f4v a = *(const f4v*)p, c = *(const f4v*)(p + 4);
    const f4v b0 = *(const f4v*)(bq + lane * 8), b1 = *(const f4v*)(bq + lane * 8 + 4);
    float d = a[0]*b0[0]+a[1]*b0[1]+a[2]*b0[2]+a[3]*b0[3]
            + c[0]*b1[0]+c[1]*b1[1]+c[2]*b1[2]+c[3]*b1[3];
#pragma unroll
    for (int off = 32; off; off >>= 1) d += __shfl_xor(d, off);
    if (lane == 0) wvec[row] = d;
  } else if (bid == 128) {               // bqbk
    __shared__ float red[256];
    red[tid] = bq[tid] * bk[tid] + bq[tid + 256] * bk[tid + 256];
    __syncthreads();
    if (tid == 0) { float s = 0.f; for (int h = 0; h < 256; ++h) s += red[h]; bqbk[0] = s; }
  } else if (bid < 129 + 2048) {         // PEQ
    const u32* fp = (const u32*)fpos_raw;
    const bool is64 = (fp[1] == 0);
    const int t = (bid - 129) * 256 + tid;
    const int tq = t >> 9, d = t & 511;
    const int pos = (int)(is64 ? fp[2 * tq] : fp[tq]);
    float pe = 0.f;
    if (pos != 0) {
      const float invf = exp2f(-(float)(d >> 1) * INVC);
      const float ang  = ((float)pos * QRY_RATE) * invf;
      pe = (d & 1) ? cosf(ang) : sinf(ang);
    }
    PEQ[t] = pe;
  } else {                               // Wo^T 32x32 tiles
    __shared__ float t[32][33];
    const int local = bid - 2177;
    const int bx = local & 15, by = local >> 4;
    const int tx = tid & 31, ty = tid >> 5;
    const int x = bx * 32 + tx;
#pragma unroll
    for (int j = 0; j < 4; ++j)
      t[ty + 8 * j][tx] = Wo[(size_t)(by * 32 + ty + 8 * j) * 512 + x];
    __syncthreads();
    const int x2 = by * 32 + tx;
#pragma unroll
    for (int j = 0; j < 4; ++j)
      WoT[(size_t)(bx * 32 + ty + 8 * j) * 512 + x2] = t[tx][ty + 8 * j];
  }
}

// ---------------- prepB: weight-product GEMMs + key prep + cvec  (512 threads) ----------------
__global__ __launch_bounds__(512) void k_prepB(
    const float* __restrict__ Wq, const float* __restrict__ Wk,
    const float* __restrict__ WoT, const float* __restrict__ Wv,
    const float* __restrict__ keys, const void* __restrict__ tpos_raw,
    const void* __restrict__ mask_raw,
    const float* __restrict__ wvec, const float* __restrict__ bqbk,
    const float* __restrict__ bv, const float* __restrict__ bo,
    _Float16* __restrict__ Mm, _Float16* __restrict__ Nt,
    _Float16* __restrict__ kp, float* __restrict__ tvec,
    float* __restrict__ cvec) {
  __shared__ char lds[40960];
  const int bid = blockIdx.x, tid = threadIdx.x;
  const int lane = tid & 63, wid = tid >> 6;
  if (bid < 8) {                         // weight products
    char *Ab = lds, *Bb = lds + 8192;
    const int wr = wid >> 2, wc = wid & 3;
    const int x = bid & 3, y = bid >> 2;
    const float* A = (y == 0 ? Wq : WoT) + (size_t)x * 128 * 512;
    const float* B = (y == 0 ? Wk : Wv);
    _Float16* out = (y == 0 ? Mm : Nt) + (size_t)x * 128 * 512;
    f4v acc[4][8] = {};
    for (int ks = 0; ks < 16; ++ks) {
      stage_f32_A(Ab, A, ks * 32, tid);
      stage_f32_B(Bb, B, ks * 32, tid);
      __syncthreads();
      h8 a[4], bf[8];
      read_fragsA(Ab, wr, lane, a);
      read_fragsB(Bb, wc, lane, bf);
      MFMA_ALL(a, bf, acc);
      __syncthreads();
    }
    const int l15 = lane & 15, hi = lane >> 4;
#pragma unroll
    for (int mi = 0; mi < 4; ++mi)
#pragma unroll
      for (int nj = 0; nj < 8; ++nj) {
        const int col = wc * 128 + nj * 16 + l15;
#pragma unroll
        for (int j = 0; j < 4; ++j) {
          const int row = wr * 64 + mi * 16 + hi * 4 + j;
          out[(size_t)row * 512 + col] = (_Float16)acc[mi][nj][j];
        }
      }
  } else if (bid < 4104) {               // key prep: 8 rows/block
    const u32* tp = (const u32*)tpos_raw;
    const bool is64 = (tp[1] == 0);
    const int row = (bid - 8) * 8 + wid;
    const int pos = (int)(is64 ? tp[2 * row] : tp[row]);
    const int d0  = lane * 8;
    const float* src = keys + (size_t)row * 512 + d0;
    const f4v a = *(const f4v*)src, b = *(const f4v*)(src + 4);
    float x[8] = {a[0], a[1], a[2], a[3], b[0], b[1], b[2], b[3]};
    if (pos != 0) {
      const float pw = (float)pos * KEY_RATE;
#pragma unroll
      for (int u = 0; u < 4; ++u) {
        const float invf = exp2f(-(float)(lane * 4 + u) * INVC);
        const float ang  = pw * invf;
        x[2*u]   += sinf(ang);
        x[2*u+1] += cosf(ang);
      }
    }
    const f4v w0 = *(const f4v*)(wvec + d0), w1 = *(const f4v*)(wvec + d0 + 4);
    float dot = 0.f;
#pragma unroll
    for (int i = 0; i < 4; ++i) dot += x[i] * w0[i] + x[4+i] * w1[i];
#pragma unroll
    for (int off = 32; off; off >>= 1) dot += __shfl_xor(dot, off);
    if (lane == 0) {
      const u32* m32 = (const u32*)mask_raw;
      const bool is32 = (m32[448] != 0);
      const bool mk = is32 ? (m32[row] != 0)
                           : (((const unsigned char*)mask_raw)[row] != 0);
      tvec[row] = mk ? -1e30f : (dot + bqbk[0]);
    }
    h8 o;
#pragma unroll
    for (int i = 0; i < 8; ++i) o[i] = (_Float16)x[i];
    *(h8*)(kp + (size_t)row * 512 + d0) = o;
  } else {                               // cvec: 8 rows/block from WoT
    const int row = (bid - 4104) * 8 + wid;
    const float* p = WoT + (size_t)row * 512 + lane * 8;
    const f4v a = *(const f4v*)p, c = *(const f4v*)(p + 4);
    const f4v b0 = *(const f4v*)(bv + lane * 8), b1 = *(const f4v*)(bv + lane * 8 + 4);
    float d = a[0]*b0[0]+a[1]*b0[1]+a[2]*b0[2]+a[3]*b0[3]
            + c[0]*b1[0]+c[1]*b1[1]+c[2]*b1[2]+c[3]*b1[3];
#pragma unroll
    for (int off = 32; off; off >>= 1) d += __shfl_xor(d, off);
    if (lane == 0) cvec[row] = SCALE * d + bo[row];
  }
}

// ---------------- mk + pv merged (paired-period pipelines, 160KB LDS) ----------------
__global__ __launch_bounds__(512, 1) void k_mkpv(
    const _Float16* __restrict__ kp, const _Float16* __restrict__ Mm,
    const float* __restrict__ values, const _Float16* __restrict__ Nt,
    _Float16* __restrict__ MKt, _Float16* __restrict__ Pt) {
  __shared__ char lds[163840];
  const int bid = blockIdx.x, tid = threadIdx.x;
  const int lane = tid & 63, wid = tid >> 6;
  const int wr = wid >> 2, wc = wid & 3;
  const int l15 = lane & 15, hi = lane >> 4;
  f4v acc[4][8] = {};
  if (bid < 256) {                       // MKt[t][c] = kp @ Mm^T
    const int tt = bid & 3, b = bid >> 2;
    const _Float16* As = kp + ((size_t)b * TKN + tt * 128) * 512;
    GLD_PIPELINE(As, Mm, acc);
    _Float16* Ob = MKt + (size_t)b * TKN * 512 + (size_t)tt * 128 * 512;
#pragma unroll
    for (int mi = 0; mi < 4; ++mi)
#pragma unroll
      for (int nj = 0; nj < 8; ++nj) {
        const int col = wc * 128 + nj * 16 + l15;
#pragma unroll
        for (int j = 0; j < 4; ++j) {
          const int row = wr * 64 + mi * 16 + hi * 4 + j;
          Ob[(size_t)row * 512 + col] = (_Float16)acc[mi][nj][j];
        }
      }
  } else {                               // Pt[e][t] = (values @ N)^T
    const int rt = (bid - 256) & 3, b = (bid - 256) >> 2;
    const float* As = values + ((size_t)b * TKN + rt * 128) * 512;
    const float* Ad = nullptr;
    REG_PIPELINE(As, Ad, Nt, acc);
    _Float16* Pb = Pt + (size_t)b * 512 * 512;
#pragma unroll
    for (int mi = 0; mi < 4; ++mi)
#pragma unroll
      for (int nj = 0; nj < 8; ++nj) {
        const int col = wc * 128 + nj * 16 + l15;
        const int t0  = rt * 128 + wr * 64 + mi * 16 + hi * 4;
        h4 o;
#pragma unroll
        for (int j = 0; j < 4; ++j) o[j] = (_Float16)acc[mi][nj][j];
        *(h4*)(Pb + (size_t)col * 512 + t0) = o;
      }
  }
}

// ---------------- scores + fused softmax (XCD-local batches, 160KB LDS) ----------------
__global__ __launch_bounds__(512, 1) void k_scores(
    const float* __restrict__ query, const float* __restrict__ PEQ,
    const _Float16* __restrict__ MKt, const float* __restrict__ tve,
    float* __restrict__ attn, _Float16* __restrict__ a16) {
  __shared__ char lds[163840];
  const int tid = threadIdx.x, lane = tid & 63, wid = tid >> 6;
  const int wr = wid >> 2, wc = wid & 3;
  const int bid = blockIdx.x;
  const int xcd = bid & 7, i = bid >> 3;
  const int qt = i & 7, b = xcd * 8 + (i >> 3);
  const float* As = query + ((size_t)b * TQ + qt * 128) * 512;
  const float* Ad = PEQ + (size_t)(qt * 128) * 512;
  const _Float16* Bs = MKt + (size_t)b * TKN * 512;
  const int l15 = lane & 15, hi = lane >> 4;
  float tv[8];
#pragma unroll
  for (int nj = 0; nj < 8; ++nj) tv[nj] = tve[b * TKN + wc * 128 + nj * 16 + l15];
  f4v acc[4][8] = {};
  REG_PIPELINE(As, Ad, Bs, acc);
  // ---- fused softmax over full 512-wide rows (red arrays reuse A0 buffer) ----
  float* red  = (float*)lds;            // [128][4]
  float* red2 = (float*)(lds + 2048);
#pragma unroll
  for (int mi = 0; mi < 4; ++mi)
#pragma unroll
    for (int nj = 0; nj < 8; ++nj) {
      const float t = tv[nj];
#pragma unroll
      for (int j = 0; j < 4; ++j) acc[mi][nj][j] += t;
    }
  float mrow[4][4];
#pragma unroll
  for (int mi = 0; mi < 4; ++mi)
#pragma unroll
    for (int j = 0; j < 4; ++j) {
      float m = acc[mi][0][j];
#pragma unroll
      for (int nj = 1; nj < 8; ++nj) m = fmaxf(m, acc[mi][nj][j]);
      m = fmaxf(m, __shfl_xor(m, 1)); m = fmaxf(m, __shfl_xor(m, 2));
      m = fmaxf(m, __shfl_xor(m, 4)); m = fmaxf(m, __shfl_xor(m, 8));
      mrow[mi][j] = m;
    }
  __syncthreads();                      // pipeline LDS reads done before reuse
  if (l15 == 0) {
#pragma unroll
    for (int mi = 0; mi < 4; ++mi)
#pragma unroll
      for (int j = 0; j < 4; ++j)
        red[(wr * 64 + mi * 16 + hi * 4 + j) * 4 + wc] = mrow[mi][j];
  }
  __syncthreads();
#pragma unroll
  for (int mi = 0; mi < 4; ++mi)
#pragma unroll
    for (int j = 0; j < 4; ++j) {
      const f4v rv = *(const f4v*)(red + (wr * 64 + mi * 16 + hi * 4 + j) * 4);
      mrow[mi][j] = fmaxf(fmaxf(rv[0], rv[1]), fmaxf(rv[2], rv[3]));
    }
  float srow[4][4];
#pragma unroll
  for (int mi = 0; mi < 4; ++mi)
#pragma unroll
    for (int j = 0; j < 4; ++j) {
      float s = 0.f;
      const float m = mrow[mi][j];
#pragma unroll
      for (int nj = 0; nj < 8; ++nj) {
        const float e = expf(acc[mi][nj][j] - m);
        acc[mi][nj][j] = e; s += e;
      }
      s += __shfl_xor(s, 1); s += __shfl_xor(s, 2);
      s += __shfl_xor(s, 4); s += __shfl_xor(s, 8);
      srow[mi][j] = s;
    }
  if (l15 == 0) {
#pragma unroll
    for (int mi = 0; mi < 4; ++mi)
#pragma unroll
      for (int j = 0; j < 4; ++j)
        red2[(wr * 64 + mi * 16 + hi * 4 + j) * 4 + wc] = srow[mi][j];
  }
  __syncthreads();
  float* Ao = attn + ((size_t)b * TQ + qt * 128) * 512;
  _Float16* Ah = a16 ? a16 + ((size_t)b * TQ + qt * 128) * 512 : nullptr;
#pragma unroll
  for (int mi = 0; mi < 4; ++mi)
#pragma unroll
    for (int j = 0; j < 4; ++j) {
      const int row = wr * 64 + mi * 16 + hi * 4 + j;
      const f4v sv = *(const f4v*)(red2 + row * 4);
      const float rinv = 1.f / (sv[0] + sv[1] + sv[2] + sv[3]);
#pragma unroll
      for (int nj = 0; nj < 8; ++nj) {
        const float v = acc[mi][nj][j] * rinv;
        const int col = wc * 128 + nj * 16 + l15;
        Ao[(size_t)row * 512 + col] = v;
        if (Ah) Ah[(size_t)row * 512 + col] = (_Float16)v;
      }
    }
}

// ---------------- out = SCALE * attn @ Pt^T + cvec (XCD-local, 160KB LDS) ----------------
template <int A16P>
__global__ __launch_bounds__(512, 1) void k_final(
    const float* __restrict__ attn, const _Float16* __restrict__ attn16,
    const _Float16* __restrict__ Pt, const float* __restrict__ cvec,
    float* __restrict__ outp) {
  __shared__ char lds[163840];
  const int tid = threadIdx.x, lane = tid & 63, wid = tid >> 6;
  const int wr = wid >> 2, wc = wid & 3;
  const int bid = blockIdx.x;
  const int xcd = bid & 7, i = bid >> 3;
  const int qt = i & 7, b = xcd * 8 + (i >> 3);
  const _Float16* Bs = Pt + (size_t)b * 512 * 512;
  const int l15 = lane & 15, hi = lane >> 4;
  f4v acc[4][8] = {};
  if (A16P) {
    const _Float16* As = attn16 + ((size_t)b * TQ + qt * 128) * 512;
    GLD_PIPELINE(As, Bs, acc);
  } else {
    const float* As = attn + ((size_t)b * TQ + qt * 128) * 512;
    const float* Ad = nullptr;
    REG_PIPELINE(As, Ad, Bs, acc);
  }
  float cv[8];
#pragma unroll
  for (int nj = 0; nj < 8; ++nj) cv[nj] = cvec[wc * 128 + nj * 16 + l15];
  float* Ob = outp + ((size_t)b * TQ + qt * 128) * 512;
#pragma unroll
  for (int mi = 0; mi < 4; ++mi)
#pragma unroll
    for (int nj = 0; nj < 8; ++nj) {
      const int col = wc * 128 + nj * 16 + l15;
#pragma unroll
      for (int j = 0; j < 4; ++j) {
        const int row = wr * 64 + mi * 16 + hi * 4 + j;
        Ob[(size_t)row * 512 + col] = SCALE * acc[mi][nj][j] + cv[nj];
      }
    }
}

// ---------------- launcher ----------------
extern "C" void kernel_launch(void* const* d_in, const int* in_sizes, int n_in,
                              void* d_out, int out_size, void* d_ws, size_t ws_size,
                              hipStream_t stream) {
  (void)in_sizes; (void)n_in; (void)out_size;
  if (ws_size < WS_NEED) return;
  const bool big = (ws_size >= WS_BIG);

  const float* query  = (const float*)d_in[0];
  const float* keys   = (const float*)d_in[1];
  const float* values = (const float*)d_in[2];
  const void*  tpos   = d_in[3];
  const void*  fpos   = d_in[4];
  const void*  mask   = d_in[5];
  const float* Wq = (const float*)d_in[6];
  const float* bq = (const float*)d_in[7];
  const float* Wk = (const float*)d_in[8];
  const float* bk = (const float*)d_in[9];
  const float* Wv = (const float*)d_in[10];
  const float* bv = (const float*)d_in[11];
  const float* Wo = (const float*)d_in[12];
  const float* bo = (const float*)d_in[13];

  char* ws = (char*)d_ws;
  _Float16* Mm   = (_Float16*)(ws + OFF_MM);
  _Float16* Nt   = (_Float16*)(ws + OFF_NT);
  float*    WoT  = (float*)   (ws + OFF_WOT);
  float*    PEQ  = (float*)   (ws + OFF_PEQ);
  float*    wvec = (float*)   (ws + OFF_W);
  float*    cvec = (float*)   (ws + OFF_C);
  float*    bqbk = (float*)   (ws + OFF_BQBK);
  float*    tvec = (float*)   (ws + OFF_T);
  _Float16* kp   = (_Float16*)(ws + OFF_KP);
  _Float16* MKt  = (_Float16*)(ws + OFF_MKT);
  _Float16* Pt   = (_Float16*)(ws + OFF_PT);
  _Float16* a16  = big ? (_Float16*)(ws + OFF_A16) : nullptr;

  float* outp = (float*)d_out;
  float* attn = outp + (size_t)64 * TQ * 512;   // output 1 region

  k_prepA<<<2433, 256, 0, stream>>>(Wk, bq, bk, Wo, fpos, wvec, bqbk, PEQ, WoT);
  k_prepB<<<4168, 512, 0, stream>>>(Wq, Wk, WoT, Wv, keys, tpos, mask,
                                    wvec, bqbk, bv, bo, Mm, Nt, kp, tvec, cvec);
  k_mkpv <<<512, 512, 0, stream>>>(kp, Mm, values, Nt, MKt, Pt);
  k_scores<<<512, 512, 0, stream>>>(query, PEQ, MKt, tvec, attn, a16);
  if (big) k_final<1><<<512, 512, 0, stream>>>(attn, a16, Pt, cvec, outp);
  else     k_final<0><<<512, 512, 0, stream>>>(attn, a16, Pt, cvec, outp);
}

// Round 16
// 300.312 us; speedup vs baseline: 1.1552x; 1.0525x over previous
//
#include <hip/hip_runtime.h>
#include <stdint.h>

#define DEVI __device__ __forceinline__

typedef __attribute__((ext_vector_type(4))) float     f4v;
typedef __attribute__((ext_vector_type(8))) _Float16  h8;
typedef __attribute__((ext_vector_type(4))) _Float16  h4;
typedef unsigned int  u32;

static constexpr int   TQ = 1024, TKN = 512;
static constexpr float KEY_RATE = 1.385f;
static constexpr float QRY_RATE = 1.0f;
static constexpr float SCALE    = 0.04419417382415922f;   // sqrt(1/512)
static constexpr float INVC     = 0.05190512648261504f;   // log2(10000)/256

// ---------------- workspace layout (bytes) ----------------
static constexpr size_t OFF_MM   = 0;                                  // fp16 [512][512]  Mm = Wq Wk^T
static constexpr size_t OFF_NT   = OFF_MM  + (size_t)512*512*2;        // fp16 [512][512]  Nt = (Wv Wo)^T
static constexpr size_t OFF_WOT  = OFF_NT  + (size_t)512*512*2;        // f32  [512][512]  Wo^T
static constexpr size_t OFF_PEQ  = OFF_WOT + (size_t)512*512*4;        // f32  [1024][512]
static constexpr size_t OFF_W    = OFF_PEQ + (size_t)1024*512*4;       // f32  [512]
static constexpr size_t OFF_C    = OFF_W   + 2048;                     // f32  [512]
static constexpr size_t OFF_BQBK = OFF_C   + 2048;                     // f32  [1]
static constexpr size_t OFF_T    = OFF_BQBK + 256;                     // f32  [64][512] tvec_eff
static constexpr size_t OFF_KP   = OFF_T   + (size_t)64*512*4;         // fp16 [64][512][512] k' = keys+pe
static constexpr size_t OFF_MKT  = OFF_KP  + (size_t)64*512*512*2;     // fp16 [64][512][512] MKt[t][c]
static constexpr size_t OFF_PT   = OFF_MKT + (size_t)64*512*512*2;     // fp16 [64][512][512] Pt[e][t]
static constexpr size_t WS_NEED  = OFF_PT  + (size_t)64*512*512*2;     // ~105 MB
static constexpr size_t OFF_A16  = WS_NEED;                            // fp16 [64][1024][512] attn fp16
static constexpr size_t WS_BIG   = OFF_A16 + (size_t)64*1024*512*2;    // ~206 MB

#define WAITV(N) asm volatile("s_waitcnt vmcnt(" #N ")" ::: "memory")
#define WAITL()  asm volatile("s_waitcnt lgkmcnt(0)" ::: "memory")
#define SCHEDB() __builtin_amdgcn_sched_barrier(0)
#define BARRAW() __builtin_amdgcn_s_barrier()

// ---------------- core helpers (BM=128, BN=512, BK=32 template) ----------------
DEVI f4v mfma16(h8 a, h8 b, f4v c) {
  return __builtin_amdgcn_mfma_f32_16x16x32_f16(a, b, c, 0, 0, 0);
}

DEVI void gld16(void* lds, const void* g) {
  __builtin_amdgcn_global_load_lds(
      (const __attribute__((address_space(1))) unsigned int*)g,
      (__attribute__((address_space(3))) unsigned int*)lds, 16, 0, 0);
}

// B panel: 512 rows x 32 cols fp16 (row stride 512): slot s holds chunk s^((r>>1)&3). 4 gld16/thread.
DEVI void stage_B(char* Bbuf, const _Float16* B, int k0, int tid) {
#pragma unroll
  for (int it = 0; it < 4; ++it) {
    const int c = (it << 9) + tid;              // 0..2047 16B chunks
    const int r = c >> 2, s = c & 3;
    const int sg = s ^ ((r >> 1) & 3);
    gld16(Bbuf + ((size_t)c << 4), B + (size_t)r * 512 + k0 + (sg << 3));
  }
}

// A tile fp16: 128 rows x 32 cols (row stride 512). 1 gld16/thread.
DEVI void stage_A16(char* Abuf, const _Float16* A, int k0, int tid) {
  const int r = tid >> 2, s = tid & 3;
  const int sg = s ^ ((r >> 1) & 3);
  gld16(Abuf + ((size_t)tid << 4), A + (size_t)r * 512 + k0 + (sg << 3));
}

// A tile fp32 source: issue loads (early) ...
DEVI void loads_A32(f4v& x0, f4v& x1, const float* A, const float* add, int k0, int tid) {
  const int r = tid >> 2, c8 = (tid & 3) << 3;
  const float* p = A + (size_t)r * 512 + k0 + c8;
  x0 = *(const f4v*)p; x1 = *(const f4v*)(p + 4);
  if (add) {
    const float* q = add + (size_t)r * 512 + k0 + c8;
    x0 += *(const f4v*)q; x1 += *(const f4v*)(q + 4);
  }
}
// ... convert+write (late)
DEVI void write_A32(char* Abuf, f4v x0, f4v x1, int tid) {
  const int r = tid >> 2;
  const int slot = (tid & 3) ^ ((r >> 1) & 3);
  h8 o;
#pragma unroll
  for (int i = 0; i < 4; ++i) { o[i] = (_Float16)x0[i]; o[4 + i] = (_Float16)x1[i]; }
  *(h8*)(Abuf + (r << 6) + (slot << 4)) = o;
}

DEVI void read_fragsA(const char* Ab, int wr, int lane, h8 (&a)[4]) {
  const int l15 = lane & 15, hi = lane >> 4;
#pragma unroll
  for (int mi = 0; mi < 4; ++mi) {
    const int r = wr * 64 + mi * 16 + l15;
    a[mi] = *(const h8*)(Ab + (r << 6) + ((hi ^ ((r >> 1) & 3)) << 4));
  }
}
DEVI void read_fragsB(const char* Bb, int wc, int lane, h8 (&b)[8]) {
  const int l15 = lane & 15, hi = lane >> 4;
#pragma unroll
  for (int nj = 0; nj < 8; ++nj) {
    const int g = wc * 128 + nj * 16 + l15;
    b[nj] = *(const h8*)(Bb + (g << 6) + ((hi ^ ((g >> 1) & 3)) << 4));
  }
}

// T5: setprio around the MFMA cluster
#define MFMA_ALL(a, bf, acc) do {                               \
  __builtin_amdgcn_s_setprio(1);                                \
  _Pragma("unroll") for (int mi = 0; mi < 4; ++mi)              \
  _Pragma("unroll") for (int nj = 0; nj < 8; ++nj)              \
      acc[mi][nj] = mfma16(a[mi], bf[nj], acc[mi][nj]);         \
  __builtin_amdgcn_s_setprio(0);                                \
} while (0)

// ---- REG-A pipeline: A f32 (+opt add) reg-staged 2-deep, B gld16 3-deep, counted vmcnt ----
// LDS map: A0@0, A1@8K, B0@16K, B1@48K, B2@80K  (112KB)
#define REG_PIPELINE(As, Ad, Bs, acc)                                              \
  {                                                                                \
    char* const Abf[2] = {lds, lds + 8192};                                        \
    char* const Bbf[3] = {lds + 16384, lds + 49152, lds + 81920};                  \
    f4v xa0, xa1, xb0, xb1;                                                        \
    loads_A32(xa0, xa1, As, Ad, 0, tid);                                           \
    loads_A32(xb0, xb1, As, Ad, 32, tid);                                          \
    SCHEDB();                                                                      \
    stage_B(Bbf[0], Bs, 0, tid);                                                   \
    stage_B(Bbf[1], Bs, 32, tid);                                                  \
    WAITV(4);                                                                      \
    write_A32(Abf[0], xa0, xa1, tid);                                              \
    WAITL(); SCHEDB(); BARRAW(); SCHEDB();                                         \
    _Pragma("unroll")                                                              \
    for (int k = 0; k < 16; ++k) {                                                 \
      if (k < 14) {                                                                \
        if ((k & 1) == 0) { loads_A32(xa0, xa1, As, Ad, (k + 2) * 32, tid); }      \
        else              { loads_A32(xb0, xb1, As, Ad, (k + 2) * 32, tid); }      \
        SCHEDB();                                                                  \
        stage_B(Bbf[(k + 2) % 3], Bs, (k + 2) * 32, tid);                          \
      }                                                                            \
      h8 a[4], bf[8];                                                              \
      read_fragsA(Abf[k & 1], wr, lane, a);                                        \
      read_fragsB(Bbf[k % 3], wc, lane, bf);                                       \
      MFMA_ALL(a, bf, acc);                                                        \
      if (k < 15) {                                                                \
        if (k < 14) { WAITV(6); } else { WAITV(0); }                               \
        if ((k & 1) == 0) write_A32(Abf[1], xb0, xb1, tid);                        \
        else              write_A32(Abf[0], xa0, xa1, tid);                        \
        WAITL(); SCHEDB(); BARRAW(); SCHEDB();                                     \
      }                                                                            \
    }                                                                              \
  }

// ---- GLD-A pipeline loop: A fp16 gld16 3-deep, B gld16 3-deep ----
// LDS map: A0@0, A1@8K, A2@16K, B0@24K, B1@56K, B2@88K  (120KB)
#define GLD_PIPELINE(As, Bs, acc)                                                  \
  {                                                                                \
    char* const Abf[3] = {lds, lds + 8192, lds + 16384};                           \
    char* const Bbf[3] = {lds + 24576, lds + 57344, lds + 90112};                  \
    stage_A16(Abf[0], As, 0, tid);  stage_B(Bbf[0], Bs, 0, tid);                   \
    stage_A16(Abf[1], As, 32, tid); stage_B(Bbf[1], Bs, 32, tid);                  \
    WAITV(5); SCHEDB(); BARRAW(); SCHEDB();                                        \
    _Pragma("unroll")                                                              \
    for (int k = 0; k < 16; ++k) {                                                 \
      if (k < 14) {                                                                \
        stage_A16(Abf[(k + 2) % 3], As, (k + 2) * 32, tid);                        \
        stage_B(Bbf[(k + 2) % 3], Bs, (k + 2) * 32, tid);                          \
      }                                                                            \
      h8 a[4], bf[8];                                                              \
      read_fragsA(Abf[k % 3], wr, lane, a);                                        \
      read_fragsB(Bbf[k % 3], wc, lane, bf);                                       \
      MFMA_ALL(a, bf, acc);                                                        \
      if (k < 14) { WAITV(5); } else if (k == 14) { WAITV(0); }                    \
      if (k < 15) { WAITL(); SCHEDB(); BARRAW(); SCHEDB(); }                       \
    }                                                                              \
  }

// reg-stage f32 tiles for the tiny weight-product GEMM (single-buffered)
DEVI void stage_f32_A(char* Abuf, const float* A, int k0, int tid) {
#pragma unroll
  for (int it = 0; it < 2; ++it) {
    const int idx = (it << 9) + tid;
    const int r = idx >> 3, c4 = idx & 7;
    f4v x = *(const f4v*)(A + (size_t)r * 512 + k0 + (c4 << 2));
    h4 o;
#pragma unroll
    for (int i = 0; i < 4; ++i) o[i] = (_Float16)x[i];
    const int slot = (c4 >> 1) ^ ((r >> 1) & 3);
    *(h4*)(Abuf + (r << 6) + (slot << 4) + ((c4 & 1) << 3)) = o;
  }
}
DEVI void stage_f32_B(char* Bbuf, const float* B, int k0, int tid) {
#pragma unroll
  for (int it = 0; it < 8; ++it) {
    const int idx = (it << 9) + tid;
    const int r = idx >> 3, c4 = idx & 7;
    f4v x = *(const f4v*)(B + (size_t)r * 512 + k0 + (c4 << 2));
    h4 o;
#pragma unroll
    for (int i = 0; i < 4; ++i) o[i] = (_Float16)x[i];
    const int slot = (c4 >> 1) ^ ((r >> 1) & 3);
    *(h4*)(Bbuf + (r << 6) + (slot << 4) + ((c4 & 1) << 3)) = o;
  }
}

// ---------------- prepA: wvec/bqbk + PEQ + Wo^T  (256 threads) ----------------
__global__ __launch_bounds__(256) void k_prepA(
    const float* __restrict__ Wk, const float* __restrict__ bq,
    const float* __restrict__ bk,
    const float* __restrict__ Wo,
    const void* __restrict__ fpos_raw,
    float* __restrict__ wvec, float* __restrict__ bqbk,
    float* __restrict__ PEQ, float* __restrict__ WoT) {
  const int bid = blockIdx.x, tid = threadIdx.x;
  if (bid < 128) {                       // wvec: 4 rows/block, 1 per wave
    const int wid = tid >> 6, lane = tid & 63;
    const int row = bid * 4 + wid;
    const float* p = Wk + (size_t)row * 512 + lane * 8;
    const f4v a = *(const f4v*)p, c = *(const f4v*)(p + 4);
    const f4v b0 = *(const f4v*)(bq + lane * 8), b1 = *(const f4v*)(bq + lane * 8 + 4);
    float d = a[0]*b0[0]+a[1]*b0[1]+a[2]*b0[2]+a[3]*b0[3]
            + c[0]*b1[0]+c[1]*b1[1]+c[2]*b1[2]+c[3]*b1[3];
#pragma unroll
    for (int off = 32; off; off >>= 1) d += __shfl_xor(d, off);
    if (lane == 0) wvec[row] = d;
  } else if (bid == 128) {               // bqbk
    __shared__ float red[256];
    red[tid] = bq[tid] * bk[tid] + bq[tid + 256] * bk[tid + 256];
    __syncthreads();
    if (tid == 0) { float s = 0.f; for (int h = 0; h < 256; ++h) s += red[h]; bqbk[0] = s; }
  } else if (bid < 129 + 2048) {         // PEQ
    const u32* fp = (const u32*)fpos_raw;
    const bool is64 = (fp[1] == 0);
    const int t = (bid - 129) * 256 + tid;
    const int tq = t >> 9, d = t & 511;
    const int pos = (int)(is64 ? fp[2 * tq] : fp[tq]);
    float pe = 0.f;
    if (pos != 0) {
      const float invf = exp2f(-(float)(d >> 1) * INVC);
      const float ang  = ((float)pos * QRY_RATE) * invf;
      pe = (d & 1) ? cosf(ang) : sinf(ang);
    }
    PEQ[t] = pe;
  } else {                               // Wo^T 32x32 tiles
    __shared__ float t[32][33];
    const int local = bid - 2177;
    const int bx = local & 15, by = local >> 4;
    const int tx = tid & 31, ty = tid >> 5;
    const int x = bx * 32 + tx;
#pragma unroll
    for (int j = 0; j < 4; ++j)
      t[ty + 8 * j][tx] = Wo[(size_t)(by * 32 + ty + 8 * j) * 512 + x];
    __syncthreads();
    const int x2 = by * 32 + tx;
#pragma unroll
    for (int j = 0; j < 4; ++j)
      WoT[(size_t)(bx * 32 + ty + 8 * j) * 512 + x2] = t[tx][ty + 8 * j];
  }
}

// ---------------- prepB: weight-product GEMMs + key prep + cvec  (512 threads) ----------------
__global__ __launch_bounds__(512) void k_prepB(
    const float* __restrict__ Wq, const float* __restrict__ Wk,
    const float* __restrict__ WoT, const float* __restrict__ Wv,
    const float* __restrict__ keys, const void* __restrict__ tpos_raw,
    const void* __restrict__ mask_raw,
    const float* __restrict__ wvec, const float* __restrict__ bqbk,
    const float* __restrict__ bv, const float* __restrict__ bo,
    _Float16* __restrict__ Mm, _Float16* __restrict__ Nt,
    _Float16* __restrict__ kp, float* __restrict__ tvec,
    float* __restrict__ cvec) {
  __shared__ char lds[40960];
  const int bid = blockIdx.x, tid = threadIdx.x;
  const int lane = tid & 63, wid = tid >> 6;
  if (bid < 8) {                         // weight products
    char *Ab = lds, *Bb = lds + 8192;
    const int wr = wid >> 2, wc = wid & 3;
    const int x = bid & 3, y = bid >> 2;
    const float* A = (y == 0 ? Wq : WoT) + (size_t)x * 128 * 512;
    const float* B = (y == 0 ? Wk : Wv);
    _Float16* out = (y == 0 ? Mm : Nt) + (size_t)x * 128 * 512;
    f4v acc[4][8] = {};
    for (int ks = 0; ks < 16; ++ks) {
      stage_f32_A(Ab, A, ks * 32, tid);
      stage_f32_B(Bb, B, ks * 32, tid);
      __syncthreads();
      h8 a[4], bf[8];
      read_fragsA(Ab, wr, lane, a);
      read_fragsB(Bb, wc, lane, bf);
      MFMA_ALL(a, bf, acc);
      __syncthreads();
    }
    const int l15 = lane & 15, hi = lane >> 4;
#pragma unroll
    for (int mi = 0; mi < 4; ++mi)
#pragma unroll
      for (int nj = 0; nj < 8; ++nj) {
        const int col = wc * 128 + nj * 16 + l15;
#pragma unroll
        for (int j = 0; j < 4; ++j) {
          const int row = wr * 64 + mi * 16 + hi * 4 + j;
          out[(size_t)row * 512 + col] = (_Float16)acc[mi][nj][j];
        }
      }
  } else if (bid < 4104) {               // key prep: 8 rows/block
    const u32* tp = (const u32*)tpos_raw;
    const bool is64 = (tp[1] == 0);
    const int row = (bid - 8) * 8 + wid;
    const int pos = (int)(is64 ? tp[2 * row] : tp[row]);
    const int d0  = lane * 8;
    const float* src = keys + (size_t)row * 512 + d0;
    const f4v a = *(const f4v*)src, b = *(const f4v*)(src + 4);
    float x[8] = {a[0], a[1], a[2], a[3], b[0], b[1], b[2], b[3]};
    if (pos != 0) {
      const float pw = (float)pos * KEY_RATE;
#pragma unroll
      for (int u = 0; u < 4; ++u) {
        const float invf = exp2f(-(float)(lane * 4 + u) * INVC);
        const float ang  = pw * invf;
        x[2*u]   += sinf(ang);
        x[2*u+1] += cosf(ang);
      }
    }
    const f4v w0 = *(const f4v*)(wvec + d0), w1 = *(const f4v*)(wvec + d0 + 4);
    float dot = 0.f;
#pragma unroll
    for (int i = 0; i < 4; ++i) dot += x[i] * w0[i] + x[4+i] * w1[i];
#pragma unroll
    for (int off = 32; off; off >>= 1) dot += __shfl_xor(dot, off);
    if (lane == 0) {
      const u32* m32 = (const u32*)mask_raw;
      const bool is32 = (m32[448] != 0);
      const bool mk = is32 ? (m32[row] != 0)
                           : (((const unsigned char*)mask_raw)[row] != 0);
      tvec[row] = mk ? -1e30f : (dot + bqbk[0]);
    }
    h8 o;
#pragma unroll
    for (int i = 0; i < 8; ++i) o[i] = (_Float16)x[i];
    *(h8*)(kp + (size_t)row * 512 + d0) = o;
  } else {                               // cvec: 8 rows/block from WoT
    const int row = (bid - 4104) * 8 + wid;
    const float* p = WoT + (size_t)row * 512 + lane * 8;
    const f4v a = *(const f4v*)p, c = *(const f4v*)(p + 4);
    const f4v b0 = *(const f4v*)(bv + lane * 8), b1 = *(const f4v*)(bv + lane * 8 + 4);
    float d = a[0]*b0[0]+a[1]*b0[1]+a[2]*b0[2]+a[3]*b0[3]
            + c[0]*b1[0]+c[1]*b1[1]+c[2]*b1[2]+c[3]*b1[3];
#pragma unroll
    for (int off = 32; off; off >>= 1) d += __shfl_xor(d, off);
    if (lane == 0) cvec[row] = SCALE * d + bo[row];
  }
}

// ---------------- mk + pv merged (counted-vmcnt pipelines) ----------------
__global__ __launch_bounds__(512, 1) void k_mkpv(
    const _Float16* __restrict__ kp, const _Float16* __restrict__ Mm,
    const float* __restrict__ values, const _Float16* __restrict__ Nt,
    _Float16* __restrict__ MKt, _Float16* __restrict__ Pt) {
  __shared__ char lds[122880];
  const int bid = blockIdx.x, tid = threadIdx.x;
  const int lane = tid & 63, wid = tid >> 6;
  const int wr = wid >> 2, wc = wid & 3;
  const int l15 = lane & 15, hi = lane >> 4;
  f4v acc[4][8] = {};
  if (bid < 256) {                       // MKt[t][c] = kp @ Mm^T
    const int tt = bid & 3, b = bid >> 2;
    const _Float16* As = kp + ((size_t)b * TKN + tt * 128) * 512;
    GLD_PIPELINE(As, Mm, acc);
    _Float16* Ob = MKt + (size_t)b * TKN * 512 + (size_t)tt * 128 * 512;
#pragma unroll
    for (int mi = 0; mi < 4; ++mi)
#pragma unroll
      for (int nj = 0; nj < 8; ++nj) {
        const int col = wc * 128 + nj * 16 + l15;
#pragma unroll
        for (int j = 0; j < 4; ++j) {
          const int row = wr * 64 + mi * 16 + hi * 4 + j;
          Ob[(size_t)row * 512 + col] = (_Float16)acc[mi][nj][j];
        }
      }
  } else {                               // Pt[e][t] = (values @ N)^T
    const int rt = (bid - 256) & 3, b = (bid - 256) >> 2;
    const float* As = values + ((size_t)b * TKN + rt * 128) * 512;
    const float* Ad = nullptr;
    REG_PIPELINE(As, Ad, Nt, acc);
    _Float16* Pb = Pt + (size_t)b * 512 * 512;
#pragma unroll
    for (int mi = 0; mi < 4; ++mi)
#pragma unroll
      for (int nj = 0; nj < 8; ++nj) {
        const int col = wc * 128 + nj * 16 + l15;
        const int t0  = rt * 128 + wr * 64 + mi * 16 + hi * 4;
        h4 o;
#pragma unroll
        for (int j = 0; j < 4; ++j) o[j] = (_Float16)acc[mi][nj][j];
        *(h4*)(Pb + (size_t)col * 512 + t0) = o;
      }
  }
}

// ---------------- scores + fused softmax (XCD-local batches) ----------------
__global__ __launch_bounds__(512, 1) void k_scores(
    const float* __restrict__ query, const float* __restrict__ PEQ,
    const _Float16* __restrict__ MKt, const float* __restrict__ tve,
    float* __restrict__ attn, _Float16* __restrict__ a16) {
  __shared__ char lds[114688];
  const int tid = threadIdx.x, lane = tid & 63, wid = tid >> 6;
  const int wr = wid >> 2, wc = wid & 3;
  const int bid = blockIdx.x;
  const int xcd = bid & 7, i = bid >> 3;
  const int qt = i & 7, b = xcd * 8 + (i >> 3);
  const float* As = query + ((size_t)b * TQ + qt * 128) * 512;
  const float* Ad = PEQ + (size_t)(qt * 128) * 512;
  const _Float16* Bs = MKt + (size_t)b * TKN * 512;
  const int l15 = lane & 15, hi = lane >> 4;
  float tv[8];
#pragma unroll
  for (int nj = 0; nj < 8; ++nj) tv[nj] = tve[b * TKN + wc * 128 + nj * 16 + l15];
  f4v acc[4][8] = {};
  REG_PIPELINE(As, Ad, Bs, acc);
  // ---- fused softmax over full 512-wide rows (red arrays reuse A0 buffer) ----
  float* red  = (float*)lds;            // [128][4]
  float* red2 = (float*)(lds + 2048);
#pragma unroll
  for (int mi = 0; mi < 4; ++mi)
#pragma unroll
    for (int nj = 0; nj < 8; ++nj) {
      const float t = tv[nj];
#pragma unroll
      for (int j = 0; j < 4; ++j) acc[mi][nj][j] += t;
    }
  float mrow[4][4];
#pragma unroll
  for (int mi = 0; mi < 4; ++mi)
#pragma unroll
    for (int j = 0; j < 4; ++j) {
      float m = acc[mi][0][j];
#pragma unroll
      for (int nj = 1; nj < 8; ++nj) m = fmaxf(m, acc[mi][nj][j]);
      m = fmaxf(m, __shfl_xor(m, 1)); m = fmaxf(m, __shfl_xor(m, 2));
      m = fmaxf(m, __shfl_xor(m, 4)); m = fmaxf(m, __shfl_xor(m, 8));
      mrow[mi][j] = m;
    }
  __syncthreads();
  if (l15 == 0) {
#pragma unroll
    for (int mi = 0; mi < 4; ++mi)
#pragma unroll
      for (int j = 0; j < 4; ++j)
        red[(wr * 64 + mi * 16 + hi * 4 + j) * 4 + wc] = mrow[mi][j];
  }
  __syncthreads();
#pragma unroll
  for (int mi = 0; mi < 4; ++mi)
#pragma unroll
    for (int j = 0; j < 4; ++j) {
      const f4v rv = *(const f4v*)(red + (wr * 64 + mi * 16 + hi * 4 + j) * 4);
      mrow[mi][j] = fmaxf(fmaxf(rv[0], rv[1]), fmaxf(rv[2], rv[3]));
    }
  float srow[4][4];
#pragma unroll
  for (int mi = 0; mi < 4; ++mi)
#pragma unroll
    for (int j = 0; j < 4; ++j) {
      float s = 0.f;
      const float m = mrow[mi][j];
#pragma unroll
      for (int nj = 0; nj < 8; ++nj) {
        const float e = expf(acc[mi][nj][j] - m);
        acc[mi][nj][j] = e; s += e;
      }
      s += __shfl_xor(s, 1); s += __shfl_xor(s, 2);
      s += __shfl_xor(s, 4); s += __shfl_xor(s, 8);
      srow[mi][j] = s;
    }
  if (l15 == 0) {
#pragma unroll
    for (int mi = 0; mi < 4; ++mi)
#pragma unroll
      for (int j = 0; j < 4; ++j)
        red2[(wr * 64 + mi * 16 + hi * 4 + j) * 4 + wc] = srow[mi][j];
  }
  __syncthreads();
  float* Ao = attn + ((size_t)b * TQ + qt * 128) * 512;
  _Float16* Ah = a16 ? a16 + ((size_t)b * TQ + qt * 128) * 512 : nullptr;
#pragma unroll
  for (int mi = 0; mi < 4; ++mi)
#pragma unroll
    for (int j = 0; j < 4; ++j) {
      const int row = wr * 64 + mi * 16 + hi * 4 + j;
      const f4v sv = *(const f4v*)(red2 + row * 4);
      const float rinv = 1.f / (sv[0] + sv[1] + sv[2] + sv[3]);
#pragma unroll
      for (int nj = 0; nj < 8; ++nj) {
        const float v = acc[mi][nj][j] * rinv;
        const int col = wc * 128 + nj * 16 + l15;
        Ao[(size_t)row * 512 + col] = v;
        if (Ah) Ah[(size_t)row * 512 + col] = (_Float16)v;
      }
    }
}

// ---------------- out = SCALE * attn @ Pt^T + cvec (XCD-local batches) ----------------
template <int A16P>
__global__ __launch_bounds__(512, 1) void k_final(
    const float* __restrict__ attn, const _Float16* __restrict__ attn16,
    const _Float16* __restrict__ Pt, const float* __restrict__ cvec,
    float* __restrict__ outp) {
  __shared__ char lds[122880];
  const int tid = threadIdx.x, lane = tid & 63, wid = tid >> 6;
  const int wr = wid >> 2, wc = wid & 3;
  const int bid = blockIdx.x;
  const int xcd = bid & 7, i = bid >> 3;
  const int qt = i & 7, b = xcd * 8 + (i >> 3);
  const _Float16* Bs = Pt + (size_t)b * 512 * 512;
  const int l15 = lane & 15, hi = lane >> 4;
  f4v acc[4][8] = {};
  if (A16P) {
    const _Float16* As = attn16 + ((size_t)b * TQ + qt * 128) * 512;
    GLD_PIPELINE(As, Bs, acc);
  } else {
    const float* As = attn + ((size_t)b * TQ + qt * 128) * 512;
    const float* Ad = nullptr;
    REG_PIPELINE(As, Ad, Bs, acc);
  }
  float cv[8];
#pragma unroll
  for (int nj = 0; nj < 8; ++nj) cv[nj] = cvec[wc * 128 + nj * 16 + l15];
  float* Ob = outp + ((size_t)b * TQ + qt * 128) * 512;
#pragma unroll
  for (int mi = 0; mi < 4; ++mi)
#pragma unroll
    for (int nj = 0; nj < 8; ++nj) {
      const int col = wc * 128 + nj * 16 + l15;
#pragma unroll
      for (int j = 0; j < 4; ++j) {
        const int row = wr * 64 + mi * 16 + hi * 4 + j;
        Ob[(size_t)row * 512 + col] = SCALE * acc[mi][nj][j] + cv[nj];
      }
    }
}

// ---------------- launcher ----------------
extern "C" void kernel_launch(void* const* d_in, const int* in_sizes, int n_in,
                              void* d_out, int out_size, void* d_ws, size_t ws_size,
                              hipStream_t stream) {
  (void)in_sizes; (void)n_in; (void)out_size;
  if (ws_size < WS_NEED) return;
  const bool big = (ws_size >= WS_BIG);

  const float* query  = (const float*)d_in[0];
  const float* keys   = (const float*)d_in[1];
  const float* values = (const float*)d_in[2];
  const void*  tpos   = d_in[3];
  const void*  fpos   = d_in[4];
  const void*  mask   = d_in[5];
  const float* Wq = (const float*)d_in[6];
  const float* bq = (const float*)d_in[7];
  const float* Wk = (const float*)d_in[8];
  const float* bk = (const float*)d_in[9];
  const float* Wv = (const float*)d_in[10];
  const float* bv = (const float*)d_in[11];
  const float* Wo = (const float*)d_in[12];
  const float* bo = (const float*)d_in[13];

  char* ws = (char*)d_ws;
  _Float16* Mm   = (_Float16*)(ws + OFF_MM);
  _Float16* Nt   = (_Float16*)(ws + OFF_NT);
  float*    WoT  = (float*)   (ws + OFF_WOT);
  float*    PEQ  = (float*)   (ws + OFF_PEQ);
  float*    wvec = (float*)   (ws + OFF_W);
  float*    cvec = (float*)   (ws + OFF_C);
  float*    bqbk = (float*)   (ws + OFF_BQBK);
  float*    tvec = (float*)   (ws + OFF_T);
  _Float16* kp   = (_Float16*)(ws + OFF_KP);
  _Float16* MKt  = (_Float16*)(ws + OFF_MKT);
  _Float16* Pt   = (_Float16*)(ws + OFF_PT);
  _Float16* a16  = big ? (_Float16*)(ws + OFF_A16) : nullptr;

  float* outp = (float*)d_out;
  float* attn = outp + (size_t)64 * TQ * 512;   // output 1 region

  k_prepA<<<2433, 256, 0, stream>>>(Wk, bq, bk, Wo, fpos, wvec, bqbk, PEQ, WoT);
  k_prepB<<<4168, 512, 0, stream>>>(Wq, Wk, WoT, Wv, keys, tpos, mask,
                                    wvec, bqbk, bv, bo, Mm, Nt, kp, tvec, cvec);
  k_mkpv <<<512, 512, 0, stream>>>(kp, Mm, values, Nt, MKt, Pt);
  k_scores<<<512, 512, 0, stream>>>(query, PEQ, MKt, tvec, attn, a16);
  if (big) k_final<1><<<512, 512, 0, stream>>>(attn, a16, Pt, cvec, outp);
  else     k_final<0><<<512, 512, 0, stream>>>(attn, a16, Pt, cvec, outp);
}